// Round 1
// baseline (952.671 us; speedup 1.0000x reference)
//
#include <hip/hip_runtime.h>

// Problem constants (from reference): B=512, T=200, NUM_Q=2048, NUM_S=512
#define BATCH_N 512
#define T_FULL  200
#define T1      199
#define NUM_Q   2048
#define NUM_S   512

// One block per student b. Thread t (t < T1) handles timestep t.
__global__ __launch_bounds__(256) void per_student_kernel(
    const float* __restrict__ p_s,
    const float* __restrict__ p_q,
    const int*   __restrict__ batch,   // (B, T, 3) int32
    float*       __restrict__ out,     // [0]=loss, [1..]=prediction, then ground_truth
    float*       __restrict__ ws)      // per-student partial losses (B floats)
{
    const int b    = blockIdx.x;
    const int tid  = threadIdx.x;
    const int lane = tid & 63;
    const int wave = tid >> 6;

    __shared__ int   wmax[4];
    __shared__ float wsum[4];
    __shared__ int   s_last;

    int q_id = 0, s_id = 0, ans = 0;
    if (tid < T1) {
        // qsa = batch[:, 1:T1+1, :]  -> time index tid+1
        const int* row = batch + ((size_t)b * T_FULL + (tid + 1)) * 3;
        q_id = row[0];
        s_id = row[1];
        ans  = row[2];
    }

    // last[b] = max over t of (s_raw > 0 ? t : -1)
    int cand = (tid < T1 && s_id > 0) ? tid : -1;
    #pragma unroll
    for (int off = 32; off > 0; off >>= 1)
        cand = max(cand, __shfl_down(cand, off, 64));
    if (lane == 0) wmax[wave] = cand;
    __syncthreads();
    if (tid == 0) {
        int m = wmax[0];
        m = max(m, wmax[1]); m = max(m, wmax[2]); m = max(m, wmax[3]);
        s_last = m;
    }
    __syncthreads();
    const int last = s_last;

    float contrib = 0.0f;
    if (tid < T1) {
        const float maskf = (tid <= last) ? 1.0f : 0.0f;
        // gathers (uncoalesced by nature)
        const float xs = p_s[(size_t)b * (T1 * NUM_S) + (size_t)tid * NUM_S + (s_id - 1)];
        const float xq = p_q[(size_t)b * (T1 * NUM_Q) + (size_t)tid * NUM_Q + (q_id - 1)];
        const float a  = (float)ans;

        const float ps = 1.0f / (1.0f + expf(-xs));
        const float pq = 1.0f / (1.0f + expf(-xq));
        const float p  = 0.5f * (ps + pq);

        // stable BCE: max(x,0) - a*x + log1p(exp(-|x|))
        const float bs = fmaxf(xs, 0.0f) - xs * a + log1pf(expf(-fabsf(xs)));
        const float bq = fmaxf(xq, 0.0f) - xq * a + log1pf(expf(-fabsf(xq)));
        contrib = maskf * (bs + bq);

        // outputs: [0]=loss, [1 .. B*T1] = prediction, [1+B*T1 .. 1+2*B*T1) = ground truth
        out[1 + (size_t)b * T1 + tid]                         = p * maskf;
        out[1 + (size_t)BATCH_N * T1 + (size_t)b * T1 + tid]  = a * maskf;
    }

    // block sum of masked BCE
    #pragma unroll
    for (int off = 32; off > 0; off >>= 1)
        contrib += __shfl_down(contrib, off, 64);
    if (lane == 0) wsum[wave] = contrib;
    __syncthreads();
    if (tid == 0) {
        const float s   = wsum[0] + wsum[1] + wsum[2] + wsum[3];
        const float cnt = (float)(last + 1);   // cnt == sum(mask)
        ws[b] = s / cnt;
    }
}

// Deterministic reduce of the 512 per-student values into out[0].
__global__ __launch_bounds__(512) void loss_reduce_kernel(
    const float* __restrict__ ws, float* __restrict__ out)
{
    const int tid  = threadIdx.x;
    const int lane = tid & 63;
    const int wave = tid >> 6;
    float v = ws[tid];
    #pragma unroll
    for (int off = 32; off > 0; off >>= 1)
        v += __shfl_down(v, off, 64);
    __shared__ float wsum[8];
    if (lane == 0) wsum[wave] = v;
    __syncthreads();
    if (tid == 0) {
        float s = 0.0f;
        #pragma unroll
        for (int i = 0; i < 8; i++) s += wsum[i];
        out[0] = s;
    }
}

extern "C" void kernel_launch(void* const* d_in, const int* in_sizes, int n_in,
                              void* d_out, int out_size, void* d_ws, size_t ws_size,
                              hipStream_t stream) {
    const float* p_s   = (const float*)d_in[0];
    const float* p_q   = (const float*)d_in[1];
    const int*   batch = (const int*)d_in[2];
    float*       out   = (float*)d_out;
    float*       ws    = (float*)d_ws;

    per_student_kernel<<<BATCH_N, 256, 0, stream>>>(p_s, p_q, batch, out, ws);
    loss_reduce_kernel<<<1, 512, 0, stream>>>(ws, out);
}